// Round 3
// baseline (447.676 us; speedup 1.0000x reference)
//
#include <hip/hip_runtime.h>
#include <hip/hip_bf16.h>

#define NTOK 16384
#define DIM  4096
#define NEXP 64
#define NE2  128
#define TOPK 8

typedef __attribute__((ext_vector_type(8)))  short short8;
typedef __attribute__((ext_vector_type(16))) float floatx16;

static __device__ inline uint fbits(float f) { union { float f; uint u; } c; c.f = f; return c.u; }
static __device__ inline float bitsf(uint u) { union { uint u; float f; } c; c.u = u; return c.f; }

// ---------------------------------------------------------------------------
// Kernel 1: prepack combined W (gate experts 0..63 -> cols 0..63, noise ->
// cols 64..127) into THREE truncation-split bf16 MFMA-B fragments
// (w1+w2+w3 == fp32 value to ~2^-24 rel; splits are exact residuals).
// Fragment (c,g,s): lane l, reg j holds split_s( W[g*32+(l&31)][c*16+(l>>5)*8+j] )
// Flat ushort index = ((c*4+g)*3+s)*512 + l*8 + j.  c=0..255 chunks of K=16.
// Total 3 MiB in d_ws.
// ---------------------------------------------------------------------------
__global__ __launch_bounds__(256) void prep_w_kernel(
    const float* __restrict__ gate_w, const float* __restrict__ noise_w,
    ushort* __restrict__ wpack)
{
  int tid = blockIdx.x * 256 + threadIdx.x;   // 65536 threads = (c,g,l)
  int l = tid & 63;
  int g = (tid >> 6) & 3;
  int c = tid >> 8;                           // 0..255
  int e = g * 32 + (l & 31);
  int k = c * 16 + ((l >> 5) & 1) * 8;
  const float* src = (e < NEXP) ? (gate_w  + (size_t)e          * DIM + k)
                                : (noise_w + (size_t)(e - NEXP) * DIM + k);
  ushort h1[8], h2[8], h3[8];
#pragma unroll
  for (int i = 0; i < 8; ++i) {
    float v  = src[i];
    uint  u  = fbits(v);
    h1[i]    = (ushort)(u >> 16);
    float r  = v - bitsf(u & 0xFFFF0000u);    // exact residual
    uint  u2 = fbits(r);
    h2[i]    = (ushort)(u2 >> 16);
    float r2 = r - bitsf(u2 & 0xFFFF0000u);   // exact residual
    h3[i]    = (ushort)(fbits(r2) >> 16);
  }
  size_t base = (size_t)((c * 4 + g) * 3) * 512;   // ushorts
  ushort* d1 = wpack + base +        (size_t)l * 8;
  ushort* d2 = wpack + base + 512  + (size_t)l * 8;
  ushort* d3 = wpack + base + 1024 + (size_t)l * 8;
#pragma unroll
  for (int i = 0; i < 8; ++i) { d1[i] = h1[i]; d2[i] = h2[i]; d3[i] = h3[i]; }
}

// ---------------------------------------------------------------------------
// Kernel 2: fused dual-GEMM (3x3 bf16-split emulated fp32, 6 MFMA products)
// + bias + noisy gating + top-8 + masked softmax + scatter.
// Grid 256 WGs x 512 thr (8 waves). WG owns 64 tokens (2 subtiles of 32);
// wave w owns K-eighth w (512). W fragments are reused for both subtiles ->
// halves wpack L2 traffic vs 32-token WGs.
// ---------------------------------------------------------------------------
__global__ __launch_bounds__(512, 2) void router_main_kernel(
    const float* __restrict__ x, const float* __restrict__ gate_b,
    const float* __restrict__ noise_b, const float* __restrict__ gauss,
    const ushort* __restrict__ wpack,
    float* __restrict__ out_sparse, float* __restrict__ out_idx)
{
  __shared__ float red[4 * 64 * NE2];   // 128 KiB: 4 reduction slices
  const int tid  = threadIdx.x;
  const int lane = tid & 63;
  const int wv   = tid >> 6;            // wave id 0..7 = K-eighth
  const int tt   = blockIdx.x;          // token tile (64 tokens)
  const int row  = lane & 31;           // A-row within 32-token subtile
  const int kg   = lane >> 5;           // k-subslice 0/1

  floatx16 acc[2][4];                   // [token-subtile][expert-group]
#pragma unroll
  for (int t2 = 0; t2 < 2; ++t2)
#pragma unroll
    for (int g = 0; g < 4; ++g)
#pragma unroll
      for (int i = 0; i < 16; ++i) acc[t2][g][i] = 0.f;

  const float*  xp0 = x + ((size_t)(tt * 64) + row) * DIM + wv * 512 + kg * 8;
  const float*  xp1 = xp0 + (size_t)32 * DIM;
  const ushort* wq  = wpack + (size_t)(wv * 32) * 6144;   // 32 chunks * 6144 ushorts

  float4 p00 = *(const float4*)(xp0);
  float4 p01 = *(const float4*)(xp0 + 4);
  float4 p10 = *(const float4*)(xp1);
  float4 p11 = *(const float4*)(xp1 + 4);

  for (int i = 0; i < 32; ++i) {        // 32 chunks of K=16
    float xa[8] = {p00.x, p00.y, p00.z, p00.w, p01.x, p01.y, p01.z, p01.w};
    float xb[8] = {p10.x, p10.y, p10.z, p10.w, p11.x, p11.y, p11.z, p11.w};
    int nx = ((i < 31) ? (i + 1) : 31) * 16;              // clamped prefetch
    p00 = *(const float4*)(xp0 + nx);
    p01 = *(const float4*)(xp0 + nx + 4);
    p10 = *(const float4*)(xp1 + nx);
    p11 = *(const float4*)(xp1 + nx + 4);

    short8 a1, a2, a3, c1, c2, c3;                        // truncation 3-split
#pragma unroll
    for (int j = 0; j < 8; ++j) {
      float v  = xa[j];
      uint  u  = fbits(v);
      a1[j]    = (short)(u >> 16);
      float r  = v - bitsf(u & 0xFFFF0000u);
      uint  u2 = fbits(r);
      a2[j]    = (short)(u2 >> 16);
      a3[j]    = (short)(fbits(r - bitsf(u2 & 0xFFFF0000u)) >> 16);
      float w  = xb[j];
      uint  uw = fbits(w);
      c1[j]    = (short)(uw >> 16);
      float rw = w - bitsf(uw & 0xFFFF0000u);
      uint  uw2 = fbits(rw);
      c2[j]    = (short)(uw2 >> 16);
      c3[j]    = (short)(fbits(rw - bitsf(uw2 & 0xFFFF0000u)) >> 16);
    }

    const ushort* wc = wq + (size_t)i * 6144;
#pragma unroll
    for (int g = 0; g < 4; ++g) {
      short8 b1 = *(const short8*)(wc + (g * 3 + 0) * 512 + lane * 8);
      short8 b2 = *(const short8*)(wc + (g * 3 + 1) * 512 + lane * 8);
      short8 b3 = *(const short8*)(wc + (g * 3 + 2) * 512 + lane * 8);
      floatx16 a = acc[0][g];
      a = __builtin_amdgcn_mfma_f32_32x32x16_bf16(a1, b1, a, 0, 0, 0);  // 1
      a = __builtin_amdgcn_mfma_f32_32x32x16_bf16(a2, b1, a, 0, 0, 0);  // 2^-8
      a = __builtin_amdgcn_mfma_f32_32x32x16_bf16(a1, b2, a, 0, 0, 0);  // 2^-8
      a = __builtin_amdgcn_mfma_f32_32x32x16_bf16(a3, b1, a, 0, 0, 0);  // 2^-16
      a = __builtin_amdgcn_mfma_f32_32x32x16_bf16(a2, b2, a, 0, 0, 0);  // 2^-16
      a = __builtin_amdgcn_mfma_f32_32x32x16_bf16(a1, b3, a, 0, 0, 0);  // 2^-16
      acc[0][g] = a;
      floatx16 b = acc[1][g];
      b = __builtin_amdgcn_mfma_f32_32x32x16_bf16(c1, b1, b, 0, 0, 0);
      b = __builtin_amdgcn_mfma_f32_32x32x16_bf16(c2, b1, b, 0, 0, 0);
      b = __builtin_amdgcn_mfma_f32_32x32x16_bf16(c1, b2, b, 0, 0, 0);
      b = __builtin_amdgcn_mfma_f32_32x32x16_bf16(c3, b1, b, 0, 0, 0);
      b = __builtin_amdgcn_mfma_f32_32x32x16_bf16(c2, b2, b, 0, 0, 0);
      b = __builtin_amdgcn_mfma_f32_32x32x16_bf16(c1, b3, b, 0, 0, 0);
      acc[1][g] = b;
    }
  }

  // ---- 3-stage deterministic reduction over 8 K-eighths.
  // C/D layout: col=lane&31, row=(r&3)+8*(r>>2)+4*(lane>>5)  [HW-verified]
  float* rw = red + (size_t)(wv & 3) * (64 * NE2);
  if (wv < 4) {                          // stage 1: waves 0-3 write slices
#pragma unroll
    for (int t2 = 0; t2 < 2; ++t2)
#pragma unroll
      for (int g = 0; g < 4; ++g)
#pragma unroll
        for (int r = 0; r < 16; ++r) {
          int tr = t2 * 32 + (r & 3) + 8 * (r >> 2) + 4 * kg;
          rw[tr * NE2 + g * 32 + (lane & 31)] = acc[t2][g][r];
        }
  }
  __syncthreads();
  if (wv >= 4) {                         // stage 2: waves 4-7 add into slices
#pragma unroll
    for (int t2 = 0; t2 < 2; ++t2)
#pragma unroll
      for (int g = 0; g < 4; ++g)
#pragma unroll
        for (int r = 0; r < 16; ++r) {
          int tr = t2 * 32 + (r & 3) + 8 * (r >> 2) + 4 * kg;
          int idx = tr * NE2 + g * 32 + (lane & 31);
          rw[idx] += acc[t2][g][r];      // disjoint elements per wave
        }
  }
  __syncthreads();
#pragma unroll
  for (int t = 0; t < 16; ++t) {         // stage 3: 4 slices -> slice 0
    int flat = t * 512 + tid;            // 8192 logits (64 tok x 128 exp)
    red[flat] = red[flat] + red[8192 + flat] + red[16384 + flat] + red[24576 + flat];
  }
  __syncthreads();

  // ---- epilogue: 8 lanes per token (64 tokens x 8 = 512 threads)
  const int tl   = tid >> 3;             // token 0..63
  const int j    = tid & 7;              // lane within token-group
  const int gtok = tt * 64 + tl;
  const float* lrow = red + tl * NE2;

  float nv[8];
#pragma unroll
  for (int i = 0; i < 8; ++i) {
    int e = j * 8 + i;
    float lg = lrow[e] + gate_b[e];
    float nz = lrow[64 + e] + noise_b[e];
    float sp = fmaxf(nz, 0.f) + log1pf(expf(-fabsf(nz)));   // jax.nn.softplus
    nv[i] = lg + gauss[(size_t)gtok * 64 + e] * sp;
  }

  float tv = 0.f; int ti = 0;
#pragma unroll
  for (int r = 0; r < TOPK; ++r) {
    float bv = nv[0]; int bi = j * 8;
#pragma unroll
    for (int i = 1; i < 8; ++i)
      if (nv[i] > bv) { bv = nv[i]; bi = j * 8 + i; }       // strict >: lower idx wins
#pragma unroll
    for (int d = 1; d < 8; d <<= 1) {                       // 8-lane all-reduce
      float ov = __shfl_xor(bv, d);
      int   oi = __shfl_xor(bi, d);
      if (ov > bv || (ov == bv && oi < bi)) { bv = ov; bi = oi; }
    }
#pragma unroll
    for (int i = 0; i < 8; ++i)                             // static-index masking
      if (bi == j * 8 + i) nv[i] = -__builtin_inff();
    if (j == r) { tv = bv; ti = bi; }                       // lane r keeps rank-r
  }

  float m  = __shfl(tv, 0, 8);                              // rank-0 value = max
  float ev = expf(tv - m);
  float es = ev;
#pragma unroll
  for (int d = 1; d < 8; d <<= 1) es += __shfl_xor(es, d);
  float p = ev / es;

  // ---- scatter into zeroed 64-wide row (reuse slice-1 LDS), coalesced write
  float* srow = red + 8192 + tl * 64;
#pragma unroll
  for (int i = 0; i < 8; ++i) srow[j * 8 + i] = 0.f;        // wave-synchronous
  srow[ti] = p;

  float* orow = out_sparse + (size_t)gtok * 64;
  float4 o0 = *(const float4*)(srow + j * 8);
  float4 o1 = *(const float4*)(srow + j * 8 + 4);
  *(float4*)(orow + j * 8)     = o0;
  *(float4*)(orow + j * 8 + 4) = o1;
  out_idx[(size_t)gtok * 8 + j] = (float)ti;
}

// ---------------------------------------------------------------------------
extern "C" void kernel_launch(void* const* d_in, const int* in_sizes, int n_in,
                              void* d_out, int out_size, void* d_ws, size_t ws_size,
                              hipStream_t stream)
{
  const float* x       = (const float*)d_in[0];
  const float* gate_w  = (const float*)d_in[1];
  const float* gate_b  = (const float*)d_in[2];
  const float* noise_w = (const float*)d_in[3];
  const float* noise_b = (const float*)d_in[4];
  const float* gauss   = (const float*)d_in[5];

  float* out_sparse = (float*)d_out;
  float* out_idx    = (float*)d_out + (size_t)NTOK * NEXP;   // indices as floats
  ushort* wpack     = (ushort*)d_ws;                         // 3 MiB

  hipLaunchKernelGGL(prep_w_kernel, dim3(256), dim3(256), 0, stream,
                     gate_w, noise_w, wpack);
  hipLaunchKernelGGL(router_main_kernel, dim3(NTOK / 64), dim3(512), 0, stream,
                     x, gate_b, noise_b, gauss, wpack, out_sparse, out_idx);
}